// Round 1
// baseline (159.878 us; speedup 1.0000x reference)
//
#include <hip/hip_runtime.h>

// Problem constants (fixed by the reference setup):
constexpr int Bv = 16, Hv = 768, Wv = 2048;
constexpr int ROWS_PER_BLOCK = 4;                 // Hv % 4 == 0 -> block stays in one image
constexpr int NROWS   = Bv * Hv;                  // 12288
constexpr int NBLOCKS = NROWS / ROWS_PER_BLOCK;   // 3072 (ws need: 3072*8 B = 24 KiB)
constexpr int MAXN    = 256;                      // max boxes per image we can stage

__global__ __launch_bounds__(256) void balancer_main(
    const float* __restrict__ loss,
    const float* __restrict__ boxes,
    const int*   __restrict__ num_gt,
    double*      __restrict__ partials)
{
    const int tid  = threadIdx.x;
    const int row0 = blockIdx.x * ROWS_PER_BLOCK;
    const int b    = row0 / Hv;                   // block-uniform image index
    const int h0   = row0 - b * Hv;               // first in-image row of this block
    const int n    = num_gt[0];

    // ---- Phase 0: issue ALL global loads for this block's 4 rows up front.
    // 8 x global_load_dwordx4 into registers (32 VGPRs, fully static indexing).
    // Their latency overlaps the box load + compaction below; the memory
    // pipeline is never drained per-row (old version: 3 barriers x 4 rows).
    float4 vbuf[ROWS_PER_BLOCK][2];
    const float4* base = (const float4*)(loss + (size_t)row0 * Wv);
    #pragma unroll
    for (int r = 0; r < ROWS_PER_BLOCK; ++r) {
        #pragma unroll
        for (int it = 0; it < 2; ++it)
            vbuf[r][it] = base[r * (Wv / 4) + it * 256 + tid];
    }

    // ---- Phase 1: one compaction pass for all 4 rows (boxes read straight
    // from global: 32 boxes * 16 B = 512 B, L1/L2-resident across blocks).
    __shared__ int  s_cnt[ROWS_PER_BLOCK];
    __shared__ int2 s_uv[ROWS_PER_BLOCK][MAXN];   // compacted [u1,u2) per row

    if (tid < ROWS_PER_BLOCK) s_cnt[tid] = 0;
    __syncthreads();                              // barrier #1 (covers cnt init)

    for (int i = tid; i < n && i < MAXN; i += 256) {
        const float4 bx = ((const float4*)boxes)[b * n + i];
        const int u1 = (int)floorf(bx.x);
        const int v1 = (int)floorf(bx.y);
        const int u2 = (int)ceilf(bx.z);
        const int v2 = (int)ceilf(bx.w);
        #pragma unroll
        for (int r = 0; r < ROWS_PER_BLOCK; ++r) {
            const int h = h0 + r;
            if (h >= v1 && h < v2) {              // E[m] ~ 4.3 of 32 per row
                const int pos = atomicAdd(&s_cnt[r], 1);
                s_uv[r][pos] = make_int2(u1, u2);
            }
        }
    }
    __syncthreads();                              // barrier #2 (last barrier)

    // ---- Phase 2: barrier-free compute. Same per-thread FP accumulation
    // order as the previous version (r outer, it inner, x/y/z/w) -> bit-identical.
    float sum = 0.0f;
    #pragma unroll
    for (int r = 0; r < ROWS_PER_BLOCK; ++r) {
        const int m = s_cnt[r];                   // block-uniform -> no divergence
        #pragma unroll
        for (int it = 0; it < 2; ++it) {
            const float4 v  = vbuf[r][it];
            const int    c0 = (it * 256 + tid) * 4;
            bool f0 = false, f1 = false, f2 = false, f3 = false;
            for (int i = 0; i < m; ++i) {         // same-addr ds_read_b64: broadcast, conflict-free
                const int2 uv = s_uv[r][i];
                f0 |= (c0     >= uv.x) & (c0     < uv.y);
                f1 |= (c0 + 1 >= uv.x) & (c0 + 1 < uv.y);
                f2 |= (c0 + 2 >= uv.x) & (c0 + 2 < uv.y);
                f3 |= (c0 + 3 >= uv.x) & (c0 + 3 < uv.y);
            }
            sum += v.x * (f0 ? 13.0f : 1.0f);
            sum += v.y * (f1 ? 13.0f : 1.0f);
            sum += v.z * (f2 ? 13.0f : 1.0f);
            sum += v.w * (f3 ? 13.0f : 1.0f);
        }
    }

    // Wave-64 shuffle reduction (fp32 leaves, tiny magnitudes -> safe).
    for (int off = 32; off > 0; off >>= 1)
        sum += __shfl_down(sum, off, 64);

    __shared__ float s_wsum[4];
    const int lane = tid & 63;
    const int wid  = tid >> 6;
    if (lane == 0) s_wsum[wid] = sum;
    __syncthreads();
    if (tid == 0) {
        double d = 0.0;
        #pragma unroll
        for (int wq = 0; wq < 4; ++wq) d += (double)s_wsum[wq];
        partials[blockIdx.x] = d;                 // plain store: no atomics, deterministic
    }
}

__global__ __launch_bounds__(256) void balancer_reduce(
    const double* __restrict__ partials, float* __restrict__ out)
{
    const int tid = threadIdx.x;
    double s = 0.0;
    for (int i = tid; i < NBLOCKS; i += 256) s += partials[i];
    for (int off = 32; off > 0; off >>= 1)
        s += __shfl_down(s, off, 64);
    __shared__ double sh[4];
    if ((tid & 63) == 0) sh[tid >> 6] = s;
    __syncthreads();
    if (tid == 0) {
        const double t = sh[0] + sh[1] + sh[2] + sh[3];
        out[0] = (float)(t / (double)((long long)Bv * Hv * Wv));
    }
}

extern "C" void kernel_launch(void* const* d_in, const int* in_sizes, int n_in,
                              void* d_out, int out_size, void* d_ws, size_t ws_size,
                              hipStream_t stream) {
    const float* loss   = (const float*)d_in[0];
    const float* boxes  = (const float*)d_in[1];
    const int*   num_gt = (const int*)d_in[2];
    double*      partials = (double*)d_ws;        // 24 KiB needed
    float*       out      = (float*)d_out;

    balancer_main<<<NBLOCKS, 256, 0, stream>>>(loss, boxes, num_gt, partials);
    balancer_reduce<<<1, 256, 0, stream>>>(partials, out);
}